// Round 1
// baseline (149.248 us; speedup 1.0000x reference)
//
#include <hip/hip_runtime.h>

// Problem constants
#define BSZ 128
#define NV 321
#define IN_DIM 336
#define OUT_DIM 96
#define NC 8
#define ROWS (BSZ * NV)   // 41088
#define KP 352            // padded K: 336 data + 1 bias + 15 zeros (11 * 32)
#define LDK 360           // LDS row stride in halfs (pad -> conflict-free ds_read_b128)
#define KSTEPS 11         // KP / 32

typedef _Float16 half8 __attribute__((ext_vector_type(8)));
typedef _Float16 half4 __attribute__((ext_vector_type(4)));
typedef float floatx4 __attribute__((ext_vector_type(4)));

// ---------------------------------------------------------------------------
// Kernel 1: convert W (8,96,336) f32 + b (8,96) f32 -> w16[(c*96+o)*352 + k]
// fp16, with bias folded at k==336 and zeros beyond.
// ---------------------------------------------------------------------------
__global__ __launch_bounds__(256) void convert_w_kernel(
    const float* __restrict__ W, const float* __restrict__ b,
    _Float16* __restrict__ w16) {
  int idx = blockIdx.x * 256 + threadIdx.x;
  if (idx >= NC * OUT_DIM * KP) return;
  int row = idx / KP;       // row = c*96 + o
  int k = idx - row * KP;
  float v;
  if (k < IN_DIM)       v = W[row * IN_DIM + k];
  else if (k == IN_DIM) v = b[row];     // b[c][o], same row index layout
  else                  v = 0.0f;
  w16[idx] = (_Float16)v;
}

// ---------------------------------------------------------------------------
// Kernel 2: main fused cluster GEMM.
// Block: 64 rows x 96 cols, 256 threads = 4 waves, wave tile 32 rows x 48 cols.
// x tile staged fp32->fp16 into LDS once (K fully resident); loop clusters,
// MFMA 16x16x32_f16, per-cluster prob-weighted accumulate into fp32 regs.
// ---------------------------------------------------------------------------
__global__ __launch_bounds__(256) void cluster_gemm_kernel(
    const float* __restrict__ x, const float* __restrict__ prob,
    const _Float16* __restrict__ w16, float* __restrict__ out) {
  __shared__ _Float16 xs[64 * LDK];

  const int tid = threadIdx.x;
  const int rbase = blockIdx.x * 64;

  // ---- stage x tile: 64 rows x 336 f32 -> f16 LDS; xs[row][336]=1.0, rest 0
  {
    int row = tid >> 2;   // 0..63
    int q = tid & 3;      // quarter-row: 84 floats each
    const float* src = x + (size_t)(rbase + row) * IN_DIM + q * 84;
    _Float16* dst = xs + row * LDK + q * 84;
#pragma unroll
    for (int j = 0; j < 21; ++j) {
      floatx4 v = *(const floatx4*)(src + j * 4);
      half4 h = {(_Float16)v[0], (_Float16)v[1], (_Float16)v[2], (_Float16)v[3]};
      *(half4*)(dst + j * 4) = h;
    }
    if (tid < 64) {
      _Float16* p = xs + tid * LDK + IN_DIM;
      p[0] = (_Float16)1.0f;     // bias lane
#pragma unroll
      for (int k = 1; k < LDK - IN_DIM; ++k) p[k] = (_Float16)0.0f;
    }
  }
  __syncthreads();

  const int lane = tid & 63;
  const int wave = tid >> 6;   // 0..3
  const int wm = wave >> 1;    // row half: 0..1 (32 rows each)
  const int wc = wave & 1;     // col half: 0..1 (48 cols each)
  const int l15 = lane & 15;
  const int lg = lane >> 4;    // 0..3

  // A fragment base: row = wm*32 + m*16 + l15, k = lg*8 + ks*32
  const _Float16* a_base = xs + (wm * 32 + l15) * LDK + lg * 8;

  // B fragment bases per n: col o = wc*48 + n*16 + l15
  const _Float16* bp0 = w16 + (size_t)(wc * 48 + 0 * 16 + l15) * KP + lg * 8;
  const _Float16* bp1 = w16 + (size_t)(wc * 48 + 1 * 16 + l15) * KP + lg * 8;
  const _Float16* bp2 = w16 + (size_t)(wc * 48 + 2 * 16 + l15) * KP + lg * 8;

  floatx4 oacc[2][3] = {};   // prob-combined fp32 accumulators

  for (int c = 0; c < NC; ++c) {
    floatx4 acc[2][3] = {};  // per-cluster MFMA accumulators
    const size_t coff = (size_t)c * OUT_DIM * KP;
#pragma unroll
    for (int ks = 0; ks < KSTEPS; ++ks) {
      half8 a0 = *(const half8*)(a_base + ks * 32);
      half8 a1 = *(const half8*)(a_base + 16 * LDK + ks * 32);
      half8 b0 = *(const half8*)(bp0 + coff + ks * 32);
      half8 b1 = *(const half8*)(bp1 + coff + ks * 32);
      half8 b2 = *(const half8*)(bp2 + coff + ks * 32);
      acc[0][0] = __builtin_amdgcn_mfma_f32_16x16x32_f16(a0, b0, acc[0][0], 0, 0, 0);
      acc[1][0] = __builtin_amdgcn_mfma_f32_16x16x32_f16(a1, b0, acc[1][0], 0, 0, 0);
      acc[0][1] = __builtin_amdgcn_mfma_f32_16x16x32_f16(a0, b1, acc[0][1], 0, 0, 0);
      acc[1][1] = __builtin_amdgcn_mfma_f32_16x16x32_f16(a1, b1, acc[1][1], 0, 0, 0);
      acc[0][2] = __builtin_amdgcn_mfma_f32_16x16x32_f16(a0, b2, acc[0][2], 0, 0, 0);
      acc[1][2] = __builtin_amdgcn_mfma_f32_16x16x32_f16(a1, b2, acc[1][2], 0, 0, 0);
    }
    // prob-weighted accumulate: out row for reg r = rbase + wm*32 + m*16 + lg*4 + r
#pragma unroll
    for (int m = 0; m < 2; ++m) {
#pragma unroll
      for (int r = 0; r < 4; ++r) {
        float p = prob[(size_t)(rbase + wm * 32 + m * 16 + lg * 4 + r) * NC + c];
        oacc[m][0][r] += p * acc[m][0][r];
        oacc[m][1][r] += p * acc[m][1][r];
        oacc[m][2][r] += p * acc[m][2][r];
      }
    }
  }

  // ---- store: C/D layout col = lane&15, row = lg*4 + r
#pragma unroll
  for (int m = 0; m < 2; ++m) {
#pragma unroll
    for (int n = 0; n < 3; ++n) {
#pragma unroll
      for (int r = 0; r < 4; ++r) {
        int grow = rbase + wm * 32 + m * 16 + lg * 4 + r;
        out[(size_t)grow * OUT_DIM + wc * 48 + n * 16 + l15] = oacc[m][n][r];
      }
    }
  }
}

// ---------------------------------------------------------------------------
extern "C" void kernel_launch(void* const* d_in, const int* in_sizes, int n_in,
                              void* d_out, int out_size, void* d_ws, size_t ws_size,
                              hipStream_t stream) {
  const float* x = (const float*)d_in[0];     // (128,321,336)
  const float* prob = (const float*)d_in[1];  // (128,321,8)
  const float* W = (const float*)d_in[2];     // (8,96,336)
  const float* b = (const float*)d_in[3];     // (8,96)
  float* out = (float*)d_out;                 // (128,321,96)
  _Float16* w16 = (_Float16*)d_ws;            // 768*352 halfs = 540,672 B

  const int wtotal = NC * OUT_DIM * KP;
  hipLaunchKernelGGL(convert_w_kernel, dim3((wtotal + 255) / 256), dim3(256), 0,
                     stream, W, b, w16);
  hipLaunchKernelGGL(cluster_gemm_kernel, dim3(ROWS / 64), dim3(256), 0, stream,
                     x, prob, w16, out);
}